// Round 1
// baseline (326.354 us; speedup 1.0000x reference)
//
#include <hip/hip_runtime.h>
#include <math.h>

#define LLEN   2048
#define NFFT   4096
#define DMODEL 256
#define NSTATE 64
#define NBATCH 16
#define PI_F   3.14159265358979323846f

// ---------------- in-LDS iterative radix-2 FFT (bitrev + DIT) ----------------
// W table: W[j] = exp(-2*pi*i*j/4096), j in [0, 2048). Works for n = 2048/4096.
__device__ inline void fft_inplace(float2* X, const float2* W, int n, int logn,
                                   int sign, int tid, int nthr) {
    // bit-reverse permutation
    for (int i = tid; i < n; i += nthr) {
        int j = (int)(__brev((unsigned)i) >> (32 - logn));
        if (j > i) { float2 t = X[i]; X[i] = X[j]; X[j] = t; }
    }
    __syncthreads();
    for (int s = 1; s <= logn; ++s) {
        const int half = 1 << (s - 1);
        const int tshift = 12 - s;             // table built for 4096
        for (int b = tid; b < (n >> 1); b += nthr) {
            const int blk = b >> (s - 1);
            const int j   = b & (half - 1);
            const int i0  = (blk << s) + j;
            const int i1  = i0 + half;
            float2 w = W[j << tshift];
            const float wy = (sign < 0) ? w.y : -w.y;
            const float2 xu = X[i0], xv = X[i1];
            const float tr = w.x * xv.x - wy * xv.y;
            const float ti = w.x * xv.y + wy * xv.x;
            X[i0] = make_float2(xu.x + tr, xu.y + ti);
            X[i1] = make_float2(xu.x - tr, xu.y - ti);
        }
        __syncthreads();
    }
}

// ---------------- K0: transpose u (32768 x 256) -> ut (256 x 32768) ----------
__global__ __launch_bounds__(256) void k_transpose_u(const float* __restrict__ u,
                                                     float* __restrict__ ut) {
    __shared__ float tile[32][33];
    const int bt0 = blockIdx.x * 32;
    const int ch0 = blockIdx.y * 32;
    const int tx = threadIdx.x, ty = threadIdx.y;
    for (int k = 0; k < 4; ++k) {
        const int r = ty + 8 * k;
        tile[r][tx] = u[(size_t)(bt0 + r) * DMODEL + ch0 + tx];
    }
    __syncthreads();
    for (int k = 0; k < 4; ++k) {
        const int r = ty + 8 * k;
        ut[(size_t)(ch0 + r) * (NBATCH * LLEN) + bt0 + tx] = tile[tx][r];
    }
}

// ---------------- K1: per-channel at_roots -> K -> Khat ----------------------
__global__ __launch_bounds__(512) void k_khat(const float* __restrict__ p_ri,
                                              const float* __restrict__ lambda_ri,
                                              const float* __restrict__ B_ri,
                                              const float* __restrict__ Ct_ri,
                                              const float* __restrict__ log_step,
                                              float2* __restrict__ Khat) {
    __shared__ float2 X[NFFT];
    __shared__ float2 W[NFFT / 2];
    __shared__ float lamx[NSTATE], lamy[NSTATE];
    __shared__ float cBx[NSTATE], cBy[NSTATE], cpx[NSTATE], cpy[NSTATE];
    __shared__ float pBx[NSTATE], pBy[NSTATE], ppv[NSTATE];
    const int d = blockIdx.x, tid = threadIdx.x, nthr = blockDim.x;

    for (int j = tid; j < NFFT / 2; j += nthr) {
        float s, c;
        sincosf(-2.f * PI_F * (float)j / (float)NFFT, &s, &c);
        W[j] = make_float2(c, s);
    }
    if (tid < NSTATE) {
        const int n = tid;
        const float px = p_ri[2 * n], py = p_ri[2 * n + 1];
        lamx[n] = lambda_ri[2 * n]; lamy[n] = lambda_ri[2 * n + 1];
        const float Bx = B_ri[(d * NSTATE + n) * 2], By = B_ri[(d * NSTATE + n) * 2 + 1];
        const float Cx = Ct_ri[(d * NSTATE + n) * 2], Cy = Ct_ri[(d * NSTATE + n) * 2 + 1];
        cBx[n] = Cx * Bx + Cy * By;  cBy[n] = Cx * By - Cy * Bx;   // conj(Ct)*B
        cpx[n] = Cx * px + Cy * py;  cpy[n] = Cx * py - Cy * px;   // conj(Ct)*p
        pBx[n] = px * Bx + py * By;  pBy[n] = px * By - py * Bx;   // conj(p)*B
        ppv[n] = px * px + py * py;                                 // conj(p)*p (real)
    }
    __syncthreads();

    const float step = expf(log_step[d]);
    const float tos = 2.f / step;
    for (int l = tid; l < LLEN; l += nthr) {
        float sn, cs;
        sincosf(2.f * PI_F * (float)l / (float)LLEN, &sn, &cs);
        const float opx = 1.f + cs, opy = sn;     // 1 + omega
        const float omx = 1.f - cs, omy = -sn;    // 1 - omega
        const float inv_op = 1.f / (opx * opx + opy * opy);
        const float gx = tos * (omx * opx + omy * opy) * inv_op;
        const float gy = tos * (omy * opx - omx * opy) * inv_op;
        const float ccx = 2.f * opx * inv_op, ccy = -2.f * opy * inv_op; // 2/(1+omega)
        float k00x = 0, k00y = 0, k01x = 0, k01y = 0;
        float k10x = 0, k10y = 0, k11x = 0, k11y = 0;
        for (int n = 0; n < NSTATE; ++n) {
            const float dx = gx - lamx[n], dy = gy - lamy[n];
            const float idn = 1.f / (dx * dx + dy * dy);
            const float ix = dx * idn, iy = -dy * idn;   // 1/(g - lam)
            k00x += cBx[n] * ix - cBy[n] * iy;  k00y += cBx[n] * iy + cBy[n] * ix;
            k01x += cpx[n] * ix - cpy[n] * iy;  k01y += cpx[n] * iy + cpy[n] * ix;
            k10x += pBx[n] * ix - pBy[n] * iy;  k10y += pBx[n] * iy + pBy[n] * ix;
            k11x += ppv[n] * ix;                k11y += ppv[n] * iy;
        }
        const float nx = k01x * k10x - k01y * k10y;
        const float ny = k01x * k10y + k01y * k10x;
        const float dpx = 1.f + k11x, dpy = k11y;
        const float idq = 1.f / (dpx * dpx + dpy * dpy);
        const float qx = (nx * dpx + ny * dpy) * idq;
        const float qy = (ny * dpx - nx * dpy) * idq;
        const float rx = k00x - qx, ry = k00y - qy;
        X[l] = make_float2(ccx * rx - ccy * ry, ccx * ry + ccy * rx);
    }
    __syncthreads();

    fft_inplace(X, W, LLEN, 11, -1, tid, nthr);   // forward DFT of at_roots
    // K[j] = Re(...)/L ; zero-pad to 4096
    for (int j = tid; j < LLEN; j += nthr) {
        const float kv = X[j].x * (1.f / (float)LLEN);
        X[j] = make_float2(kv, 0.f);
        X[LLEN + j] = make_float2(0.f, 0.f);
    }
    __syncthreads();
    fft_inplace(X, W, NFFT, 12, -1, tid, nthr);   // Khat = DFT_4096(K_pad)
    for (int f = tid; f < NFFT; f += nthr) Khat[(size_t)d * NFFT + f] = X[f];
}

// ---------------- K2: conv per (channel, batch-pair) -------------------------
__global__ __launch_bounds__(256) void k_conv(const float* __restrict__ ut,
                                              const float2* __restrict__ Khat,
                                              float* __restrict__ yt) {
    __shared__ float2 X[NFFT];
    __shared__ float2 W[NFFT / 2];
    const int blk = blockIdx.x;
    const int ch = blk >> 3;
    const int pair = blk & 7;
    const int tid = threadIdx.x, nthr = blockDim.x;
    const float* u0 = ut + (size_t)ch * (NBATCH * LLEN) + (size_t)(2 * pair) * LLEN;
    const float* u1 = u0 + LLEN;

    for (int j = tid; j < NFFT / 2; j += nthr) {
        float s, c;
        sincosf(-2.f * PI_F * (float)j / (float)NFFT, &s, &c);
        W[j] = make_float2(c, s);
    }
    for (int i = tid; i < LLEN; i += nthr) {
        X[i] = make_float2(u0[i], u1[i]);         // pack two real batches
        X[LLEN + i] = make_float2(0.f, 0.f);
    }
    __syncthreads();

    fft_inplace(X, W, NFFT, 12, -1, tid, nthr);

    const float2* H = Khat + (size_t)ch * NFFT;
    for (int f = tid; f <= NFFT / 2; f += nthr) {
        const int fb = (NFFT - f) & (NFFT - 1);
        const float2 Za = X[f], Zb = X[fb];
        // U0 = (Za + conj(Zb))/2 ; U1 = (Za - conj(Zb))/(2i)
        const float u0x = 0.5f * (Za.x + Zb.x), u0y = 0.5f * (Za.y - Zb.y);
        const float u1x = 0.5f * (Za.y + Zb.y), u1y = -0.5f * (Za.x - Zb.x);
        const float2 Ha = H[f];
        const float y0x = u0x * Ha.x - u0y * Ha.y, y0y = u0x * Ha.y + u0y * Ha.x;
        const float y1x = u1x * Ha.x - u1y * Ha.y, y1y = u1x * Ha.y + u1y * Ha.x;
        X[f] = make_float2(y0x - y1y, y0y + y1x); // Y0 + i*Y1
        if (fb != f) {
            const float2 Hb = H[fb];
            const float b0x = u0x, b0y = -u0y, b1x = u1x, b1y = -u1y; // conj
            const float z0x = b0x * Hb.x - b0y * Hb.y, z0y = b0x * Hb.y + b0y * Hb.x;
            const float z1x = b1x * Hb.x - b1y * Hb.y, z1y = b1x * Hb.y + b1y * Hb.x;
            X[fb] = make_float2(z0x - z1y, z0y + z1x);
        }
    }
    __syncthreads();

    fft_inplace(X, W, NFFT, 12, +1, tid, nthr);   // inverse (scale at store)

    float* y0o = yt + (size_t)ch * (NBATCH * LLEN) + (size_t)(2 * pair) * LLEN;
    float* y1o = y0o + LLEN;
    const float sc = 1.f / (float)NFFT;
    for (int i = tid; i < LLEN; i += nthr) {
        y0o[i] = X[i].x * sc;
        y1o[i] = X[i].y * sc;
    }
}

// ---------------- K3: transpose back + skip connection -----------------------
__global__ __launch_bounds__(256) void k_transpose_y(const float* __restrict__ yt,
                                                     const float* __restrict__ u,
                                                     const float* __restrict__ Dp,
                                                     float* __restrict__ out) {
    __shared__ float tile[32][33];
    const int bt0 = blockIdx.x * 32;
    const int ch0 = blockIdx.y * 32;
    const int tx = threadIdx.x, ty = threadIdx.y;
    for (int k = 0; k < 4; ++k) {
        const int r = ty + 8 * k;
        tile[r][tx] = yt[(size_t)(ch0 + r) * (NBATCH * LLEN) + bt0 + tx];
    }
    __syncthreads();
    const float dp = Dp[ch0 + tx];
    for (int k = 0; k < 4; ++k) {
        const int r = ty + 8 * k;
        const size_t idx = (size_t)(bt0 + r) * DMODEL + ch0 + tx;
        out[idx] = tile[tx][r] + dp * u[idx];
    }
}

extern "C" void kernel_launch(void* const* d_in, const int* in_sizes, int n_in,
                              void* d_out, int out_size, void* d_ws, size_t ws_size,
                              hipStream_t stream) {
    const float* u         = (const float*)d_in[0];
    const float* p_ri      = (const float*)d_in[1];
    const float* lambda_ri = (const float*)d_in[2];
    const float* B_ri      = (const float*)d_in[3];
    const float* Ct_ri     = (const float*)d_in[4];
    const float* Dp        = (const float*)d_in[5];
    const float* log_step  = (const float*)d_in[6];
    float* out = (float*)d_out;

    // workspace layout: Khat (256*4096 float2 = 8 MB) | yt (16*2048*256 f32 = 33.5 MB)
    float2* Khat = (float2*)d_ws;
    float*  yt   = (float*)((char*)d_ws + (size_t)DMODEL * NFFT * sizeof(float2));
    float*  ut   = out;   // reuse d_out as transpose scratch (fully overwritten later)

    k_transpose_u<<<dim3(NBATCH * LLEN / 32, DMODEL / 32), dim3(32, 8), 0, stream>>>(u, ut);
    k_khat<<<DMODEL, 512, 0, stream>>>(p_ri, lambda_ri, B_ri, Ct_ri, log_step, Khat);
    k_conv<<<DMODEL * (NBATCH / 2), 256, 0, stream>>>(ut, Khat, yt);
    k_transpose_y<<<dim3(NBATCH * LLEN / 32, DMODEL / 32), dim3(32, 8), 0, stream>>>(yt, u, Dp, out);
}

// Round 2
// 190.926 us; speedup vs baseline: 1.7093x; 1.7093x over previous
//
#include <hip/hip_runtime.h>
#include <math.h>

#define LLEN   2048
#define NFFT   4096
#define DMODEL 256
#define NSTATE 64
#define NBATCH 16
#define PI_F   3.14159265358979323846f

#define PADIDX(a) ((a) + ((a) >> 4))
#define LDSN (NFFT + (NFFT >> 4))   // 4352 floats per SoA plane

__device__ inline float frcp(float x) { return __builtin_amdgcn_rcpf(x); }

// radix-4 butterfly in place: args are (x0,x1,x2,x3) of a stride-subseq;
// writes X_k into slot k. S = -1 forward, +1 inverse.
#define RADIX4(ar0,ai0,ar1,ai1,ar2,ai2,ar3,ai3,S) do {                      \
    float s0r=(ar0)+(ar2), s0i=(ai0)+(ai2);                                 \
    float s1r=(ar0)-(ar2), s1i=(ai0)-(ai2);                                 \
    float s2r=(ar1)+(ar3), s2i=(ai1)+(ai3);                                 \
    float s3r=(ar1)-(ar3), s3i=(ai1)-(ai3);                                 \
    (ar0)=s0r+s2r; (ai0)=s0i+s2i;                                           \
    (ar2)=s0r-s2r; (ai2)=s0i-s2i;                                           \
    (ar1)=s1r-(S)*s3i; (ai1)=s1i+(S)*s3r;                                   \
    (ar3)=s1r+(S)*s3i; (ai3)=s1i-(S)*s3r;                                   \
} while (0)

// 16-point DFT in registers. Output X[u] (u = k0 + 4*k2) lands in slot 4*k0 + k2.
template<int SIGN>
__device__ inline void dft16(float xr[16], float xi[16]) {
    const float S = (float)SIGN;
    const float C1 = 0.9238795325112867f, S1 = 0.3826834323650898f;
    const float C2 = 0.7071067811865476f;
    RADIX4(xr[0],xi[0], xr[4],xi[4], xr[8],xi[8],  xr[12],xi[12], S);
    RADIX4(xr[1],xi[1], xr[5],xi[5], xr[9],xi[9],  xr[13],xi[13], S);
    RADIX4(xr[2],xi[2], xr[6],xi[6], xr[10],xi[10],xr[14],xi[14], S);
    RADIX4(xr[3],xi[3], xr[7],xi[7], xr[11],xi[11],xr[15],xi[15], S);
#define TW(idx, wr_, wi_) { float tr = xr[idx]*(wr_) - xi[idx]*(wi_);       \
    xi[idx] = xr[idx]*(wi_) + xi[idx]*(wr_); xr[idx] = tr; }
    TW(5,  C1,  S*S1);   // w16^1
    TW(6,  C2,  S*C2);   // w16^2
    TW(7,  S1,  S*C1);   // w16^3
    TW(9,  C2,  S*C2);   // w16^2
    TW(10, 0.f, S);      // w16^4
    TW(11, -C2, S*C2);   // w16^6
    TW(13, S1,  S*C1);   // w16^3
    TW(14, -C2, S*C2);   // w16^6
    TW(15, -C1, -S*S1);  // w16^9
#undef TW
    RADIX4(xr[0],xi[0],  xr[1],xi[1],  xr[2],xi[2],  xr[3],xi[3],  S);
    RADIX4(xr[4],xi[4],  xr[5],xi[5],  xr[6],xi[6],  xr[7],xi[7],  S);
    RADIX4(xr[8],xi[8],  xr[9],xi[9],  xr[10],xi[10],xr[11],xi[11],S);
    RADIX4(xr[12],xi[12],xr[13],xi[13],xr[14],xi[14],xr[15],xi[15],S);
}

// 8-point DFT in registers, natural-order output.
template<int SIGN>
__device__ inline void dft8(float xr[8], float xi[8]) {
    const float S = (float)SIGN;
    const float C2 = 0.7071067811865476f;
    RADIX4(xr[0],xi[0], xr[2],xi[2], xr[4],xi[4], xr[6],xi[6], S); // E[k] @ 2k
    RADIX4(xr[1],xi[1], xr[3],xi[3], xr[5],xi[5], xr[7],xi[7], S); // O[k] @ 2k+1
    { float tr = xr[3]*C2 - xi[3]*(S*C2); xi[3] = xr[3]*(S*C2) + xi[3]*C2; xr[3] = tr; }
    { float tr = -S*xi[5]; xi[5] = S*xr[5]; xr[5] = tr; }
    { float tr = xr[7]*(-C2) - xi[7]*(S*C2); xi[7] = xr[7]*(S*C2) + xi[7]*(-C2); xr[7] = tr; }
    float br[8], bi[8];
#pragma unroll
    for (int k = 0; k < 4; ++k) {
        br[k]   = xr[2*k] + xr[2*k+1]; bi[k]   = xi[2*k] + xi[2*k+1];
        br[k+4] = xr[2*k] - xr[2*k+1]; bi[k+4] = xi[2*k] - xi[2*k+1];
    }
#pragma unroll
    for (int k = 0; k < 8; ++k) { xr[k] = br[k]; xi[k] = bi[k]; }
}

__device__ inline void store16(float* Xr, float* Xi, const float xr[16],
                               const float xi[16], int base, int L) {
#pragma unroll
    for (int k0 = 0; k0 < 4; ++k0)
#pragma unroll
        for (int k2 = 0; k2 < 4; ++k2) {
            int a = base + (k0 + 4 * k2) * L;
            int s = 4 * k0 + k2;
            Xr[PADIDX(a)] = xr[s];
            Xi[PADIDX(a)] = xi[s];
        }
}

// one radix-16 Stockham stage (L>1): read stride m = N/16
template<int SIGN>
__device__ inline void fft_stage16(float* Xr, float* Xi, int j, int m, int L, bool active) {
    float xr[16], xi[16];
    const int p = j & (L - 1);
    if (active) {
#pragma unroll
        for (int t = 0; t < 16; ++t) {
            int a = j + t * m;
            xr[t] = Xr[PADIDX(a)]; xi[t] = Xi[PADIDX(a)];
        }
        float sn, cn;
        __sincosf(((float)SIGN * 2.f * PI_F) * (float)p / (float)(16 * L), &sn, &cn);
        float wr = cn, wi = sn;
#pragma unroll
        for (int t = 1; t < 16; ++t) {
            float tr = xr[t]*wr - xi[t]*wi;
            xi[t] = xr[t]*wi + xi[t]*wr; xr[t] = tr;
            float nr = wr*cn - wi*sn; wi = wr*sn + wi*cn; wr = nr;
        }
        dft16<SIGN>(xr, xi);
    }
    __syncthreads();
    if (active) store16(Xr, Xi, xr, xi, 16 * j - 15 * p, L);
    __syncthreads();
}

// 4096-point FFT, 256 threads, 16 elems/thread. ZHI: input known zero for idx>=2048.
template<int SIGN, bool ZHI>
__device__ inline void fft4096(float* Xr, float* Xi, int tid) {
    {   // stage 0: L=1
        float xr[16], xi[16];
#pragma unroll
        for (int t = 0; t < 16; ++t) {
            if (ZHI && t >= 8) { xr[t] = 0.f; xi[t] = 0.f; }
            else { int a = tid + t * 256; xr[t] = Xr[PADIDX(a)]; xi[t] = Xi[PADIDX(a)]; }
        }
        dft16<SIGN>(xr, xi);
        __syncthreads();
        store16(Xr, Xi, xr, xi, 16 * tid, 1);
        __syncthreads();
    }
    fft_stage16<SIGN>(Xr, Xi, tid, 256, 16, true);
    fft_stage16<SIGN>(Xr, Xi, tid, 256, 256, true);
}

// 2048-point FFT, radices [8,16,16]
template<int SIGN>
__device__ inline void fft2048(float* Xr, float* Xi, int tid) {
    {   // stage 0: radix-8, L=1
        float xr[8], xi[8];
#pragma unroll
        for (int t = 0; t < 8; ++t) {
            int a = tid + t * 256;
            xr[t] = Xr[PADIDX(a)]; xi[t] = Xi[PADIDX(a)];
        }
        dft8<SIGN>(xr, xi);
        __syncthreads();
#pragma unroll
        for (int u = 0; u < 8; ++u) {
            int a = 8 * tid + u;
            Xr[PADIDX(a)] = xr[u]; Xi[PADIDX(a)] = xi[u];
        }
        __syncthreads();
    }
    fft_stage16<SIGN>(Xr, Xi, tid, 128, 8,   tid < 128);
    fft_stage16<SIGN>(Xr, Xi, tid, 128, 128, tid < 128);
}

// ---------------- K0: transpose u (32768 x 256) -> ut (256 x 32768) ----------
__global__ __launch_bounds__(256) void k_transpose_u(const float* __restrict__ u,
                                                     float* __restrict__ ut) {
    __shared__ float tile[32][33];
    const int bt0 = blockIdx.x * 32, ch0 = blockIdx.y * 32;
    const int tx = threadIdx.x, ty = threadIdx.y;
    for (int k = 0; k < 4; ++k) {
        const int r = ty + 8 * k;
        tile[r][tx] = u[(size_t)(bt0 + r) * DMODEL + ch0 + tx];
    }
    __syncthreads();
    for (int k = 0; k < 4; ++k) {
        const int r = ty + 8 * k;
        ut[(size_t)(ch0 + r) * (NBATCH * LLEN) + bt0 + tx] = tile[tx][r];
    }
}

// ---------------- K1a: at_roots, one l per thread ----------------------------
__global__ __launch_bounds__(256) void k_atroots(const float* __restrict__ p_ri,
                                                 const float* __restrict__ lambda_ri,
                                                 const float* __restrict__ B_ri,
                                                 const float* __restrict__ Ct_ri,
                                                 const float* __restrict__ log_step,
                                                 float2* __restrict__ ar_out) {
    __shared__ float4 c0[NSTATE];   // cBx, cBy, cpx, cpy
    __shared__ float4 c1[NSTATE];   // pBx, pBy, ppv, 0
    __shared__ float2 lam[NSTATE];
    const int d = blockIdx.x >> 3;
    const int l = ((blockIdx.x & 7) << 8) | threadIdx.x;
    const int tid = threadIdx.x;
    if (tid < NSTATE) {
        const int n = tid;
        const float px = p_ri[2*n], py = p_ri[2*n+1];
        lam[n] = make_float2(lambda_ri[2*n], lambda_ri[2*n+1]);
        const float Bx = B_ri[(d*NSTATE+n)*2], By = B_ri[(d*NSTATE+n)*2+1];
        const float Cx = Ct_ri[(d*NSTATE+n)*2], Cy = Ct_ri[(d*NSTATE+n)*2+1];
        c0[n] = make_float4(Cx*Bx + Cy*By, Cx*By - Cy*Bx,
                            Cx*px + Cy*py, Cx*py - Cy*px);
        c1[n] = make_float4(px*Bx + py*By, px*By - py*Bx, px*px + py*py, 0.f);
    }
    __syncthreads();

    const float tos = 2.f * __expf(-log_step[d]);
    float sn, cs;
    sincosf(2.f * PI_F * (float)l / (float)LLEN, &sn, &cs);
    const float opx = 1.f + cs, opy = sn;
    const float omx = 1.f - cs, omy = -sn;
    const float inv_op = frcp(opx*opx + opy*opy);
    const float gx = tos * (omx*opx + omy*opy) * inv_op;
    const float gy = tos * (omy*opx - omx*opy) * inv_op;
    const float ccx = 2.f * opx * inv_op, ccy = -2.f * opy * inv_op;

    float k00x = 0, k00y = 0, k01x = 0, k01y = 0;
    float k10x = 0, k10y = 0, k11x = 0, k11y = 0;
    for (int n = 0; n < NSTATE; ++n) {
        const float2 lm = lam[n];
        const float dx = gx - lm.x, dy = gy - lm.y;
        const float idn = frcp(dx*dx + dy*dy);
        const float ix = dx * idn, iy = -dy * idn;
        const float4 a = c0[n];
        const float4 b = c1[n];
        k00x += a.x*ix - a.y*iy;  k00y += a.x*iy + a.y*ix;
        k01x += a.z*ix - a.w*iy;  k01y += a.z*iy + a.w*ix;
        k10x += b.x*ix - b.y*iy;  k10y += b.x*iy + b.y*ix;
        k11x += b.z*ix;           k11y += b.z*iy;
    }
    const float nx = k01x*k10x - k01y*k10y;
    const float ny = k01x*k10y + k01y*k10x;
    const float dpx = 1.f + k11x, dpy = k11y;
    const float idq = frcp(dpx*dpx + dpy*dpy);
    const float qx = (nx*dpx + ny*dpy) * idq;
    const float qy = (ny*dpx - nx*dpy) * idq;
    const float rx = k00x - qx, ry = k00y - qy;
    ar_out[(size_t)d * LLEN + l] = make_float2(ccx*rx - ccy*ry, ccx*ry + ccy*rx);
}

// ---------------- K1b: at_roots -> K -> Khat ---------------------------------
__global__ __launch_bounds__(256, 4) void k_khat(const float2* __restrict__ ar_in,
                                                 float2* __restrict__ Khat) {
    __shared__ float Xr[LDSN], Xi[LDSN];
    const int d = blockIdx.x, tid = threadIdx.x;
    for (int l = tid; l < LLEN; l += 256) {
        float2 v = ar_in[(size_t)d * LLEN + l];
        Xr[PADIDX(l)] = v.x; Xi[PADIDX(l)] = v.y;
    }
    __syncthreads();
    fft2048<-1>(Xr, Xi, tid);
    for (int l = tid; l < LLEN; l += 256) {
        const int pl = PADIDX(l);
        Xr[pl] = Xr[pl] * (1.f / (float)LLEN);
        Xi[pl] = 0.f;
    }
    __syncthreads();
    fft4096<-1, true>(Xr, Xi, tid);
    for (int f = tid; f < NFFT; f += 256)
        Khat[(size_t)d * NFFT + f] = make_float2(Xr[PADIDX(f)], Xi[PADIDX(f)]);
}

// ---------------- K2: conv per (channel, batch-pair) -------------------------
__global__ __launch_bounds__(256, 4) void k_conv(const float* __restrict__ ut,
                                                 const float2* __restrict__ Khat,
                                                 float* __restrict__ yt) {
    __shared__ float Xr[LDSN], Xi[LDSN];
    const int ch = blockIdx.x >> 3, pair = blockIdx.x & 7, tid = threadIdx.x;
    const float* u0 = ut + (size_t)ch * (NBATCH * LLEN) + (size_t)(2 * pair) * LLEN;
    const float* u1 = u0 + LLEN;
    for (int i = tid; i < LLEN; i += 256) {
        Xr[PADIDX(i)] = u0[i]; Xi[PADIDX(i)] = u1[i];
    }
    __syncthreads();
    fft4096<-1, true>(Xr, Xi, tid);

    const float2* H = Khat + (size_t)ch * NFFT;
    for (int f = tid; f <= NFFT / 2; f += 256) {
        const int fb = (NFFT - f) & (NFFT - 1);
        const int pf = PADIDX(f), pfb = PADIDX(fb);
        const float zax = Xr[pf], zay = Xi[pf];
        const float zbx = Xr[pfb], zby = Xi[pfb];
        const float u0x = 0.5f * (zax + zbx), u0y = 0.5f * (zay - zby);
        const float u1x = 0.5f * (zay + zby), u1y = -0.5f * (zax - zbx);
        const float2 Ha = H[f];
        const float y0x = u0x*Ha.x - u0y*Ha.y, y0y = u0x*Ha.y + u0y*Ha.x;
        const float y1x = u1x*Ha.x - u1y*Ha.y, y1y = u1x*Ha.y + u1y*Ha.x;
        Xr[pf] = y0x - y1y; Xi[pf] = y0y + y1x;
        if (fb != f) {
            const float2 Hb = H[fb];
            const float z0x = u0x*Hb.x + u0y*Hb.y, z0y = u0x*Hb.y - u0y*Hb.x;
            const float z1x = u1x*Hb.x + u1y*Hb.y, z1y = u1x*Hb.y - u1y*Hb.x;
            Xr[pfb] = z0x - z1y; Xi[pfb] = z0y + z1x;
        }
    }
    __syncthreads();
    fft4096<+1, false>(Xr, Xi, tid);

    float* y0o = yt + (size_t)ch * (NBATCH * LLEN) + (size_t)(2 * pair) * LLEN;
    float* y1o = y0o + LLEN;
    const float sc = 1.f / (float)NFFT;
    for (int i = tid; i < LLEN; i += 256) {
        y0o[i] = Xr[PADIDX(i)] * sc;
        y1o[i] = Xi[PADIDX(i)] * sc;
    }
}

// ---------------- K3: transpose back + skip connection -----------------------
__global__ __launch_bounds__(256) void k_transpose_y(const float* __restrict__ yt,
                                                     const float* __restrict__ u,
                                                     const float* __restrict__ Dp,
                                                     float* __restrict__ out) {
    __shared__ float tile[32][33];
    const int bt0 = blockIdx.x * 32, ch0 = blockIdx.y * 32;
    const int tx = threadIdx.x, ty = threadIdx.y;
    for (int k = 0; k < 4; ++k) {
        const int r = ty + 8 * k;
        tile[r][tx] = yt[(size_t)(ch0 + r) * (NBATCH * LLEN) + bt0 + tx];
    }
    __syncthreads();
    const float dp = Dp[ch0 + tx];
    for (int k = 0; k < 4; ++k) {
        const int r = ty + 8 * k;
        const size_t idx = (size_t)(bt0 + r) * DMODEL + ch0 + tx;
        out[idx] = tile[tx][r] + dp * u[idx];
    }
}

extern "C" void kernel_launch(void* const* d_in, const int* in_sizes, int n_in,
                              void* d_out, int out_size, void* d_ws, size_t ws_size,
                              hipStream_t stream) {
    const float* u         = (const float*)d_in[0];
    const float* p_ri      = (const float*)d_in[1];
    const float* lambda_ri = (const float*)d_in[2];
    const float* B_ri      = (const float*)d_in[3];
    const float* Ct_ri     = (const float*)d_in[4];
    const float* Dp        = (const float*)d_in[5];
    const float* log_step  = (const float*)d_in[6];
    float* out = (float*)d_out;

    // ws layout: Khat (256*4096 float2 = 8 MB) | yt (33.5 MB).
    // at_roots scratch (4 MB) aliases the yt region (consumed before k_conv writes yt).
    float2* Khat = (float2*)d_ws;
    float*  yt   = (float*)((char*)d_ws + (size_t)DMODEL * NFFT * sizeof(float2));
    float2* ar   = (float2*)yt;
    float*  ut   = out;   // reuse d_out as transpose scratch (fully overwritten later)

    k_transpose_u<<<dim3(NBATCH * LLEN / 32, DMODEL / 32), dim3(32, 8), 0, stream>>>(u, ut);
    k_atroots<<<DMODEL * 8, 256, 0, stream>>>(p_ri, lambda_ri, B_ri, Ct_ri, log_step, ar);
    k_khat<<<DMODEL, 256, 0, stream>>>(ar, Khat);
    k_conv<<<DMODEL * (NBATCH / 2), 256, 0, stream>>>(ut, Khat, yt);
    k_transpose_y<<<dim3(NBATCH * LLEN / 32, DMODEL / 32), dim3(32, 8), 0, stream>>>(yt, u, Dp, out);
}

// Round 3
// 185.301 us; speedup vs baseline: 1.7612x; 1.0304x over previous
//
#include <hip/hip_runtime.h>
#include <math.h>

#define LLEN   2048
#define NFFT   4096
#define DMODEL 256
#define NSTATE 64
#define NBATCH 16
#define PI_F   3.14159265358979323846f

#define PADIDX(a) ((a) + ((a) >> 4))
#define LDSN (NFFT + (NFFT >> 4))   // 4352 float2 = 34816 B

__device__ inline float frcp(float x) { return __builtin_amdgcn_rcpf(x); }

#define RADIX4(ar0,ai0,ar1,ai1,ar2,ai2,ar3,ai3,S) do {                      \
    float s0r=(ar0)+(ar2), s0i=(ai0)+(ai2);                                 \
    float s1r=(ar0)-(ar2), s1i=(ai0)-(ai2);                                 \
    float s2r=(ar1)+(ar3), s2i=(ai1)+(ai3);                                 \
    float s3r=(ar1)-(ar3), s3i=(ai1)-(ai3);                                 \
    (ar0)=s0r+s2r; (ai0)=s0i+s2i;                                           \
    (ar2)=s0r-s2r; (ai2)=s0i-s2i;                                           \
    (ar1)=s1r-(S)*s3i; (ai1)=s1i+(S)*s3r;                                   \
    (ar3)=s1r+(S)*s3i; (ai3)=s1i-(S)*s3r;                                   \
} while (0)

// 16-point DFT in registers. Output X[u] (u = k0 + 4*k2) lands in slot 4*k0 + k2.
template<int SIGN>
__device__ inline void dft16(float xr[16], float xi[16]) {
    const float S = (float)SIGN;
    const float C1 = 0.9238795325112867f, S1 = 0.3826834323650898f;
    const float C2 = 0.7071067811865476f;
    RADIX4(xr[0],xi[0], xr[4],xi[4], xr[8],xi[8],  xr[12],xi[12], S);
    RADIX4(xr[1],xi[1], xr[5],xi[5], xr[9],xi[9],  xr[13],xi[13], S);
    RADIX4(xr[2],xi[2], xr[6],xi[6], xr[10],xi[10],xr[14],xi[14], S);
    RADIX4(xr[3],xi[3], xr[7],xi[7], xr[11],xi[11],xr[15],xi[15], S);
#define TW(idx, wr_, wi_) { float tr = xr[idx]*(wr_) - xi[idx]*(wi_);       \
    xi[idx] = xr[idx]*(wi_) + xi[idx]*(wr_); xr[idx] = tr; }
    TW(5,  C1,  S*S1);
    TW(6,  C2,  S*C2);
    TW(7,  S1,  S*C1);
    TW(9,  C2,  S*C2);
    TW(10, 0.f, S);
    TW(11, -C2, S*C2);
    TW(13, S1,  S*C1);
    TW(14, -C2, S*C2);
    TW(15, -C1, -S*S1);
#undef TW
    RADIX4(xr[0],xi[0],  xr[1],xi[1],  xr[2],xi[2],  xr[3],xi[3],  S);
    RADIX4(xr[4],xi[4],  xr[5],xi[5],  xr[6],xi[6],  xr[7],xi[7],  S);
    RADIX4(xr[8],xi[8],  xr[9],xi[9],  xr[10],xi[10],xr[11],xi[11],S);
    RADIX4(xr[12],xi[12],xr[13],xi[13],xr[14],xi[14],xr[15],xi[15],S);
}

// 8-point DFT in registers, natural-order output.
template<int SIGN>
__device__ inline void dft8(float xr[8], float xi[8]) {
    const float S = (float)SIGN;
    const float C2 = 0.7071067811865476f;
    RADIX4(xr[0],xi[0], xr[2],xi[2], xr[4],xi[4], xr[6],xi[6], S);
    RADIX4(xr[1],xi[1], xr[3],xi[3], xr[5],xi[5], xr[7],xi[7], S);
    { float tr = xr[3]*C2 - xi[3]*(S*C2); xi[3] = xr[3]*(S*C2) + xi[3]*C2; xr[3] = tr; }
    { float tr = -S*xi[5]; xi[5] = S*xr[5]; xr[5] = tr; }
    { float tr = xr[7]*(-C2) - xi[7]*(S*C2); xi[7] = xr[7]*(S*C2) + xi[7]*(-C2); xr[7] = tr; }
    float br[8], bi[8];
#pragma unroll
    for (int k = 0; k < 4; ++k) {
        br[k]   = xr[2*k] + xr[2*k+1]; bi[k]   = xi[2*k] + xi[2*k+1];
        br[k+4] = xr[2*k] - xr[2*k+1]; bi[k+4] = xi[2*k] - xi[2*k+1];
    }
#pragma unroll
    for (int k = 0; k < 8; ++k) { xr[k] = br[k]; xi[k] = bi[k]; }
}

// twiddle powers w^t, log-depth build, then apply to x[1..15]
template<int SIGN>
__device__ inline void tw_apply16(float xr[16], float xi[16], float ang) {
    float wr[16], wi[16];
    __sincosf(ang, &wi[1], &wr[1]);
#pragma unroll
    for (int k = 1; k < 8; ++k) {
        wr[2*k]   = wr[k]*wr[k] - wi[k]*wi[k];
        wi[2*k]   = 2.f * wr[k] * wi[k];
        wr[2*k+1] = wr[k]*wr[k+1] - wi[k]*wi[k+1];
        wi[2*k+1] = wr[k]*wi[k+1] + wi[k]*wr[k+1];
    }
#pragma unroll
    for (int t = 1; t < 16; ++t) {
        float tr = xr[t]*wr[t] - xi[t]*wi[t];
        xi[t] = xr[t]*wi[t] + xi[t]*wr[t];
        xr[t] = tr;
    }
}

// one radix-16 Stockham stage. M = read stride, L = current sub-FFT len.
// PRUNE valid only for the final L=256 stage of a 4096 FFT: keep a<2048.
template<int SIGN, int M, int L, bool PRUNE>
__device__ inline void stage16(float2* X, int j, bool active) {
    float xr[16], xi[16];
    const int p = j & (L - 1);
    if (active) {
#pragma unroll
        for (int t = 0; t < 16; ++t) {
            float2 v = X[PADIDX(j + t * M)];
            xr[t] = v.x; xi[t] = v.y;
        }
        tw_apply16<SIGN>(xr, xi, ((float)SIGN * 2.f * PI_F / (float)(16 * L)) * (float)p);
        dft16<SIGN>(xr, xi);
    }
    __syncthreads();
    if (active) {
        const int base = 16 * j - 15 * p;
#pragma unroll
        for (int k0 = 0; k0 < 4; ++k0)
#pragma unroll
            for (int k2 = 0; k2 < 4; ++k2) {
                const int u = k0 + 4 * k2;
                if (!PRUNE || u < 8) {
                    const int a = base + u * L;
                    X[PADIDX(a)] = make_float2(xr[4*k0+k2], xi[4*k0+k2]);
                }
            }
    }
    __syncthreads();
}

// 4096-pt FFT, 256 threads, 16/thread. ZHI: input zero for idx>=2048 (skip reads).
// PRUNE: only outputs idx<2048 needed (skip half of final-stage stores).
template<int SIGN, bool ZHI, bool PRUNE>
__device__ inline void fft4096_f2(float2* X, int tid) {
    float xr[16], xi[16];
#pragma unroll
    for (int t = 0; t < 16; ++t) {
        if (ZHI && t >= 8) { xr[t] = 0.f; xi[t] = 0.f; }
        else { float2 v = X[PADIDX(tid + t * 256)]; xr[t] = v.x; xi[t] = v.y; }
    }
    dft16<SIGN>(xr, xi);
    __syncthreads();
#pragma unroll
    for (int k0 = 0; k0 < 4; ++k0)
#pragma unroll
        for (int k2 = 0; k2 < 4; ++k2)
            X[PADIDX(16 * tid + k0 + 4 * k2)] = make_float2(xr[4*k0+k2], xi[4*k0+k2]);
    __syncthreads();
    stage16<SIGN, 256, 16,  false>(X, tid, true);
    stage16<SIGN, 256, 256, PRUNE>(X, tid, true);
}

// 2048-pt FFT, radices [8,16,16]
template<int SIGN>
__device__ inline void fft2048_f2(float2* X, int tid) {
    float xr[8], xi[8];
#pragma unroll
    for (int t = 0; t < 8; ++t) {
        float2 v = X[PADIDX(tid + t * 256)];
        xr[t] = v.x; xi[t] = v.y;
    }
    dft8<SIGN>(xr, xi);
    __syncthreads();
#pragma unroll
    for (int u = 0; u < 8; ++u)
        X[PADIDX(8 * tid + u)] = make_float2(xr[u], xi[u]);
    __syncthreads();
    stage16<SIGN, 128, 8,   false>(X, tid, tid < 128);
    stage16<SIGN, 128, 128, false>(X, tid, tid < 128);
}

// ---- K_pre: blocks [0,256) = fused at_roots+Khat per channel;
//      blocks [256, 256+8192) = transpose u tiles -------------------------------
__global__ __launch_bounds__(256, 4) void k_pre(const float* __restrict__ u,
                                                const float* __restrict__ p_ri,
                                                const float* __restrict__ lambda_ri,
                                                const float* __restrict__ B_ri,
                                                const float* __restrict__ Ct_ri,
                                                const float* __restrict__ log_step,
                                                float* __restrict__ ut,
                                                float2* __restrict__ Khat) {
    __shared__ float2 X[LDSN];
    __shared__ float4 c0[NSTATE], c1[NSTATE];
    __shared__ float2 lam[NSTATE];
    const int tid = threadIdx.x;

    if (blockIdx.x >= DMODEL) {
        // ---- transpose tile ----
        const int blk = blockIdx.x - DMODEL;
        const int bt0 = (blk & 1023) * 32;
        const int ch0 = (blk >> 10) * 32;
        float* tile = (float*)X;   // 32x33 floats
        const int tx = tid & 31, ty = tid >> 5;
#pragma unroll
        for (int k = 0; k < 4; ++k) {
            const int r = ty + 8 * k;
            tile[r * 33 + tx] = u[(size_t)(bt0 + r) * DMODEL + ch0 + tx];
        }
        __syncthreads();
#pragma unroll
        for (int k = 0; k < 4; ++k) {
            const int r = ty + 8 * k;
            ut[(size_t)(ch0 + r) * (NBATCH * LLEN) + bt0 + tx] = tile[tx * 33 + r];
        }
        return;
    }

    // ---- fused at_roots + Khat for channel d ----
    const int d = blockIdx.x;
    if (tid < NSTATE) {
        const int n = tid;
        const float px = p_ri[2*n], py = p_ri[2*n+1];
        lam[n] = make_float2(lambda_ri[2*n], lambda_ri[2*n+1]);
        const float Bx = B_ri[(d*NSTATE+n)*2], By = B_ri[(d*NSTATE+n)*2+1];
        const float Cx = Ct_ri[(d*NSTATE+n)*2], Cy = Ct_ri[(d*NSTATE+n)*2+1];
        c0[n] = make_float4(Cx*Bx + Cy*By, Cx*By - Cy*Bx,
                            Cx*px + Cy*py, Cx*py - Cy*px);
        c1[n] = make_float4(px*Bx + py*By, px*By - py*Bx, px*px + py*py, 0.f);
    }
    __syncthreads();

    const float tos = 2.f * __expf(-log_step[d]);
    for (int kk = 0; kk < 8; kk += 4) {
        float gx[4], gy[4], ccx[4], ccy[4];
#pragma unroll
        for (int jj = 0; jj < 4; ++jj) {
            const int l = tid + (kk + jj) * 256;
            float sn, cs;
            sincosf(2.f * PI_F * (float)l / (float)LLEN, &sn, &cs);
            const float opx = 1.f + cs, opy = sn;
            const float omx = 1.f - cs, omy = -sn;
            const float inv_op = frcp(opx*opx + opy*opy);
            gx[jj] = tos * (omx*opx + omy*opy) * inv_op;
            gy[jj] = tos * (omy*opx - omx*opy) * inv_op;
            ccx[jj] = 2.f * opx * inv_op; ccy[jj] = -2.f * opy * inv_op;
        }
        float k00x[4] = {0,0,0,0}, k00y[4] = {0,0,0,0};
        float k01x[4] = {0,0,0,0}, k01y[4] = {0,0,0,0};
        float k10x[4] = {0,0,0,0}, k10y[4] = {0,0,0,0};
        float k11x[4] = {0,0,0,0}, k11y[4] = {0,0,0,0};
        for (int n = 0; n < NSTATE; ++n) {
            const float4 a = c0[n];
            const float4 b = c1[n];
            const float2 lm = lam[n];
#pragma unroll
            for (int jj = 0; jj < 4; ++jj) {
                const float dx = gx[jj] - lm.x, dy = gy[jj] - lm.y;
                const float idn = frcp(dx*dx + dy*dy);
                const float ix = dx * idn, iy = -dy * idn;
                k00x[jj] += a.x*ix - a.y*iy;  k00y[jj] += a.x*iy + a.y*ix;
                k01x[jj] += a.z*ix - a.w*iy;  k01y[jj] += a.z*iy + a.w*ix;
                k10x[jj] += b.x*ix - b.y*iy;  k10y[jj] += b.x*iy + b.y*ix;
                k11x[jj] += b.z*ix;           k11y[jj] += b.z*iy;
            }
        }
#pragma unroll
        for (int jj = 0; jj < 4; ++jj) {
            const float nx = k01x[jj]*k10x[jj] - k01y[jj]*k10y[jj];
            const float ny = k01x[jj]*k10y[jj] + k01y[jj]*k10x[jj];
            const float dpx = 1.f + k11x[jj], dpy = k11y[jj];
            const float idq = frcp(dpx*dpx + dpy*dpy);
            const float qx = (nx*dpx + ny*dpy) * idq;
            const float qy = (ny*dpx - nx*dpy) * idq;
            const float rx = k00x[jj] - qx, ry = k00y[jj] - qy;
            X[PADIDX(tid + (kk + jj) * 256)] =
                make_float2(ccx[jj]*rx - ccy[jj]*ry, ccx[jj]*ry + ccy[jj]*rx);
        }
    }
    __syncthreads();

    fft2048_f2<-1>(X, tid);
    for (int l = tid; l < LLEN; l += 256) {
        const int q = PADIDX(l);
        float2 v = X[q];
        X[q] = make_float2(v.x * (1.f / (float)LLEN), 0.f);
    }
    __syncthreads();
    fft4096_f2<-1, true, false>(X, tid);
    const float isc = 1.f / (float)NFFT;     // pre-scale for the inverse FFT in k_conv
    for (int f = tid; f < NFFT; f += 256) {
        float2 v = X[PADIDX(f)];
        Khat[(size_t)d * NFFT + f] = make_float2(v.x * isc, v.y * isc);
    }
}

// ---- K_conv: per (channel, batch-pair) ---------------------------------------
__global__ __launch_bounds__(256, 4) void k_conv(const float* __restrict__ ut,
                                                 const float2* __restrict__ Khat,
                                                 float* __restrict__ yt) {
    __shared__ float2 X[LDSN];
    const int ch = blockIdx.x >> 3, pair = blockIdx.x & 7, tid = threadIdx.x;
    const float4* u0 = (const float4*)(ut + (size_t)ch * (NBATCH * LLEN) + (size_t)(2 * pair) * LLEN);
    const float4* u1 = u0 + LLEN / 4;
#pragma unroll
    for (int k = 0; k < 2; ++k) {
        const int v4 = tid + k * 256;
        const float4 a = u0[v4], b = u1[v4];
        const int base = 4 * v4;
        X[PADIDX(base + 0)] = make_float2(a.x, b.x);
        X[PADIDX(base + 1)] = make_float2(a.y, b.y);
        X[PADIDX(base + 2)] = make_float2(a.z, b.z);
        X[PADIDX(base + 3)] = make_float2(a.w, b.w);
    }
    __syncthreads();
    fft4096_f2<-1, true, false>(X, tid);

    const float2* H = Khat + (size_t)ch * NFFT;
    for (int f = tid; f <= NFFT / 2; f += 256) {
        const int fb = (NFFT - f) & (NFFT - 1);
        const float2 Za = X[PADIDX(f)], Zb = X[PADIDX(fb)];
        const float u0x = 0.5f * (Za.x + Zb.x), u0y = 0.5f * (Za.y - Zb.y);
        const float u1x = 0.5f * (Za.y + Zb.y), u1y = -0.5f * (Za.x - Zb.x);
        const float2 Ha = H[f];
        const float y0x = u0x*Ha.x - u0y*Ha.y, y0y = u0x*Ha.y + u0y*Ha.x;
        const float y1x = u1x*Ha.x - u1y*Ha.y, y1y = u1x*Ha.y + u1y*Ha.x;
        X[PADIDX(f)] = make_float2(y0x - y1y, y0y + y1x);
        if (fb != f) {
            const float2 Hb = H[fb];
            const float z0x = u0x*Hb.x + u0y*Hb.y, z0y = u0x*Hb.y - u0y*Hb.x;
            const float z1x = u1x*Hb.x + u1y*Hb.y, z1y = u1x*Hb.y - u1y*Hb.x;
            X[PADIDX(fb)] = make_float2(z0x - z1y, z0y + z1x);
        }
    }
    __syncthreads();
    fft4096_f2<+1, false, true>(X, tid);   // pruned: only t<2048 stored

    float* y0o = yt + (size_t)ch * (NBATCH * LLEN) + (size_t)(2 * pair) * LLEN;
    float* y1o = y0o + LLEN;
    for (int i = tid; i < LLEN; i += 256) {
        const float2 v = X[PADIDX(i)];
        y0o[i] = v.x;
        y1o[i] = v.y;
    }
}

// ---- K_post: transpose back + skip -------------------------------------------
__global__ __launch_bounds__(256) void k_post(const float* __restrict__ yt,
                                              const float* __restrict__ u,
                                              const float* __restrict__ Dp,
                                              float* __restrict__ out) {
    __shared__ float tile[32][33];
    const int bt0 = blockIdx.x * 32, ch0 = blockIdx.y * 32;
    const int tx = threadIdx.x, ty = threadIdx.y;
    for (int k = 0; k < 4; ++k) {
        const int r = ty + 8 * k;
        tile[r][tx] = yt[(size_t)(ch0 + r) * (NBATCH * LLEN) + bt0 + tx];
    }
    __syncthreads();
    const float dp = Dp[ch0 + tx];
    for (int k = 0; k < 4; ++k) {
        const int r = ty + 8 * k;
        const size_t idx = (size_t)(bt0 + r) * DMODEL + ch0 + tx;
        out[idx] = tile[tx][r] + dp * u[idx];
    }
}

extern "C" void kernel_launch(void* const* d_in, const int* in_sizes, int n_in,
                              void* d_out, int out_size, void* d_ws, size_t ws_size,
                              hipStream_t stream) {
    const float* u         = (const float*)d_in[0];
    const float* p_ri      = (const float*)d_in[1];
    const float* lambda_ri = (const float*)d_in[2];
    const float* B_ri      = (const float*)d_in[3];
    const float* Ct_ri     = (const float*)d_in[4];
    const float* Dp        = (const float*)d_in[5];
    const float* log_step  = (const float*)d_in[6];
    float* out = (float*)d_out;

    // ws layout: Khat (256*4096 float2 = 8 MB) | yt (33.5 MB)
    float2* Khat = (float2*)d_ws;
    float*  yt   = (float*)((char*)d_ws + (size_t)DMODEL * NFFT * sizeof(float2));
    float*  ut   = out;   // d_out doubles as transpose scratch (fully overwritten by k_post)

    k_pre<<<DMODEL + 8192, 256, 0, stream>>>(u, p_ri, lambda_ri, B_ri, Ct_ri, log_step, ut, Khat);
    k_conv<<<DMODEL * (NBATCH / 2), 256, 0, stream>>>(ut, Khat, yt);
    k_post<<<dim3(NBATCH * LLEN / 32, DMODEL / 32), dim3(32, 8), 0, stream>>>(yt, u, Dp, out);
}

// Round 4
// 177.098 us; speedup vs baseline: 1.8428x; 1.0463x over previous
//
#include <hip/hip_runtime.h>
#include <math.h>

#define LLEN   2048
#define NFFT   4096
#define DMODEL 256
#define NSTATE 64
#define NBATCH 16
#define PI_F   3.14159265358979323846f

#define PADIDX(a) ((a) + ((a) >> 4))
#define LDSN  (NFFT + (NFFT >> 4))   // 4352 float2 = 34816 B (k_conv)
#define LDSN2 (LLEN + (LLEN >> 4))   // 2176 float2 = 17408 B (k_mix)
#define KSTRIDE 2056                 // per-channel stride for Hc (f2), f=0..2048 + pad

__device__ inline float frcp(float x) { return __builtin_amdgcn_rcpf(x); }

#define RADIX4(ar0,ai0,ar1,ai1,ar2,ai2,ar3,ai3,S) do {                      \
    float s0r=(ar0)+(ar2), s0i=(ai0)+(ai2);                                 \
    float s1r=(ar0)-(ar2), s1i=(ai0)-(ai2);                                 \
    float s2r=(ar1)+(ar3), s2i=(ai1)+(ai3);                                 \
    float s3r=(ar1)-(ar3), s3i=(ai1)-(ai3);                                 \
    (ar0)=s0r+s2r; (ai0)=s0i+s2i;                                           \
    (ar2)=s0r-s2r; (ai2)=s0i-s2i;                                           \
    (ar1)=s1r-(S)*s3i; (ai1)=s1i+(S)*s3r;                                   \
    (ar3)=s1r+(S)*s3i; (ai3)=s1i-(S)*s3r;                                   \
} while (0)

template<int SIGN>
__device__ inline void dft16(float xr[16], float xi[16]) {
    const float S = (float)SIGN;
    const float C1 = 0.9238795325112867f, S1 = 0.3826834323650898f;
    const float C2 = 0.7071067811865476f;
    RADIX4(xr[0],xi[0], xr[4],xi[4], xr[8],xi[8],  xr[12],xi[12], S);
    RADIX4(xr[1],xi[1], xr[5],xi[5], xr[9],xi[9],  xr[13],xi[13], S);
    RADIX4(xr[2],xi[2], xr[6],xi[6], xr[10],xi[10],xr[14],xi[14], S);
    RADIX4(xr[3],xi[3], xr[7],xi[7], xr[11],xi[11],xr[15],xi[15], S);
#define TW(idx, wr_, wi_) { float tr = xr[idx]*(wr_) - xi[idx]*(wi_);       \
    xi[idx] = xr[idx]*(wi_) + xi[idx]*(wr_); xr[idx] = tr; }
    TW(5,  C1,  S*S1);
    TW(6,  C2,  S*C2);
    TW(7,  S1,  S*C1);
    TW(9,  C2,  S*C2);
    TW(10, 0.f, S);
    TW(11, -C2, S*C2);
    TW(13, S1,  S*C1);
    TW(14, -C2, S*C2);
    TW(15, -C1, -S*S1);
#undef TW
    RADIX4(xr[0],xi[0],  xr[1],xi[1],  xr[2],xi[2],  xr[3],xi[3],  S);
    RADIX4(xr[4],xi[4],  xr[5],xi[5],  xr[6],xi[6],  xr[7],xi[7],  S);
    RADIX4(xr[8],xi[8],  xr[9],xi[9],  xr[10],xi[10],xr[11],xi[11],S);
    RADIX4(xr[12],xi[12],xr[13],xi[13],xr[14],xi[14],xr[15],xi[15],S);
}

template<int SIGN>
__device__ inline void dft8(float xr[8], float xi[8]) {
    const float S = (float)SIGN;
    const float C2 = 0.7071067811865476f;
    RADIX4(xr[0],xi[0], xr[2],xi[2], xr[4],xi[4], xr[6],xi[6], S);
    RADIX4(xr[1],xi[1], xr[3],xi[3], xr[5],xi[5], xr[7],xi[7], S);
    { float tr = xr[3]*C2 - xi[3]*(S*C2); xi[3] = xr[3]*(S*C2) + xi[3]*C2; xr[3] = tr; }
    { float tr = -S*xi[5]; xi[5] = S*xr[5]; xr[5] = tr; }
    { float tr = xr[7]*(-C2) - xi[7]*(S*C2); xi[7] = xr[7]*(S*C2) + xi[7]*(-C2); xr[7] = tr; }
    float br[8], bi[8];
#pragma unroll
    for (int k = 0; k < 4; ++k) {
        br[k]   = xr[2*k] + xr[2*k+1]; bi[k]   = xi[2*k] + xi[2*k+1];
        br[k+4] = xr[2*k] - xr[2*k+1]; bi[k+4] = xi[2*k] - xi[2*k+1];
    }
#pragma unroll
    for (int k = 0; k < 8; ++k) { xr[k] = br[k]; xi[k] = bi[k]; }
}

template<int SIGN>
__device__ inline void tw_apply16(float xr[16], float xi[16], float ang) {
    float wr[16], wi[16];
    __sincosf(ang, &wi[1], &wr[1]);
#pragma unroll
    for (int k = 1; k < 8; ++k) {
        wr[2*k]   = wr[k]*wr[k] - wi[k]*wi[k];
        wi[2*k]   = 2.f * wr[k] * wi[k];
        wr[2*k+1] = wr[k]*wr[k+1] - wi[k]*wi[k+1];
        wi[2*k+1] = wr[k]*wi[k+1] + wi[k]*wr[k+1];
    }
#pragma unroll
    for (int t = 1; t < 16; ++t) {
        float tr = xr[t]*wr[t] - xi[t]*wi[t];
        xi[t] = xr[t]*wi[t] + xi[t]*wr[t];
        xr[t] = tr;
    }
}

// one radix-16 Stockham stage. M = read stride, L = current sub-FFT len.
template<int SIGN, int M, int L, bool PRUNE>
__device__ inline void stage16(float2* X, int j, bool active) {
    float xr[16], xi[16];
    const int p = j & (L - 1);
    if (active) {
#pragma unroll
        for (int t = 0; t < 16; ++t) {
            float2 v = X[PADIDX(j + t * M)];
            xr[t] = v.x; xi[t] = v.y;
        }
        tw_apply16<SIGN>(xr, xi, ((float)SIGN * 2.f * PI_F / (float)(16 * L)) * (float)p);
        dft16<SIGN>(xr, xi);
    }
    __syncthreads();
    if (active) {
        const int base = 16 * j - 15 * p;
#pragma unroll
        for (int k0 = 0; k0 < 4; ++k0)
#pragma unroll
            for (int k2 = 0; k2 < 4; ++k2) {
                const int u = k0 + 4 * k2;
                if (!PRUNE || u < 8) {
                    const int a = base + u * L;
                    X[PADIDX(a)] = make_float2(xr[4*k0+k2], xi[4*k0+k2]);
                }
            }
    }
    __syncthreads();
}

// 4096-pt FFT, 256 threads, 16/thread.
template<int SIGN, bool ZHI, bool PRUNE>
__device__ inline void fft4096_f2(float2* X, int tid) {
    float xr[16], xi[16];
#pragma unroll
    for (int t = 0; t < 16; ++t) {
        if (ZHI && t >= 8) { xr[t] = 0.f; xi[t] = 0.f; }
        else { float2 v = X[PADIDX(tid + t * 256)]; xr[t] = v.x; xi[t] = v.y; }
    }
    dft16<SIGN>(xr, xi);
    __syncthreads();
#pragma unroll
    for (int k0 = 0; k0 < 4; ++k0)
#pragma unroll
        for (int k2 = 0; k2 < 4; ++k2)
            X[PADIDX(16 * tid + k0 + 4 * k2)] = make_float2(xr[4*k0+k2], xi[4*k0+k2]);
    __syncthreads();
    stage16<SIGN, 256, 16,  false>(X, tid, true);
    stage16<SIGN, 256, 256, PRUNE>(X, tid, true);
}

// 2048-pt FFT, radices [8,16,16]
template<int SIGN>
__device__ inline void fft2048_f2(float2* X, int tid) {
    float xr[8], xi[8];
#pragma unroll
    for (int t = 0; t < 8; ++t) {
        float2 v = X[PADIDX(tid + t * 256)];
        xr[t] = v.x; xi[t] = v.y;
    }
    dft8<SIGN>(xr, xi);
    __syncthreads();
#pragma unroll
    for (int u = 0; u < 8; ++u)
        X[PADIDX(8 * tid + u)] = make_float2(xr[u], xi[u]);
    __syncthreads();
    stage16<SIGN, 128, 8,   false>(X, tid, tid < 128);
    stage16<SIGN, 128, 128, false>(X, tid, tid < 128);
}

// ---- K_ar: at_roots, one l per thread (2048 blocks) --------------------------
__global__ __launch_bounds__(256) void k_ar(const float* __restrict__ p_ri,
                                            const float* __restrict__ lambda_ri,
                                            const float* __restrict__ B_ri,
                                            const float* __restrict__ Ct_ri,
                                            const float* __restrict__ log_step,
                                            float2* __restrict__ ar_out) {
    __shared__ float4 c0[NSTATE], c1[NSTATE];
    __shared__ float2 lam[NSTATE];
    const int d = blockIdx.x >> 3;
    const int l = ((blockIdx.x & 7) << 8) | threadIdx.x;
    const int tid = threadIdx.x;
    if (tid < NSTATE) {
        const int n = tid;
        const float px = p_ri[2*n], py = p_ri[2*n+1];
        lam[n] = make_float2(lambda_ri[2*n], lambda_ri[2*n+1]);
        const float Bx = B_ri[(d*NSTATE+n)*2], By = B_ri[(d*NSTATE+n)*2+1];
        const float Cx = Ct_ri[(d*NSTATE+n)*2], Cy = Ct_ri[(d*NSTATE+n)*2+1];
        c0[n] = make_float4(Cx*Bx + Cy*By, Cx*By - Cy*Bx,
                            Cx*px + Cy*py, Cx*py - Cy*px);
        c1[n] = make_float4(px*Bx + py*By, px*By - py*Bx, px*px + py*py, 0.f);
    }
    __syncthreads();

    const float tos = 2.f * __expf(-log_step[d]);
    float sn, cs;
    sincosf(2.f * PI_F * (float)l / (float)LLEN, &sn, &cs);
    const float opx = 1.f + cs, opy = sn;
    const float omx = 1.f - cs, omy = -sn;
    const float inv_op = frcp(opx*opx + opy*opy);
    const float gx = tos * (omx*opx + omy*opy) * inv_op;
    const float gy = tos * (omy*opx - omx*opy) * inv_op;
    const float ccx = 2.f * opx * inv_op, ccy = -2.f * opy * inv_op;

    float k00x = 0, k00y = 0, k01x = 0, k01y = 0;
    float k10x = 0, k10y = 0, k11x = 0, k11y = 0;
    for (int n = 0; n < NSTATE; ++n) {
        const float2 lm = lam[n];
        const float dx = gx - lm.x, dy = gy - lm.y;
        const float idn = frcp(dx*dx + dy*dy);
        const float ix = dx * idn, iy = -dy * idn;
        const float4 a = c0[n];
        const float4 b = c1[n];
        k00x += a.x*ix - a.y*iy;  k00y += a.x*iy + a.y*ix;
        k01x += a.z*ix - a.w*iy;  k01y += a.z*iy + a.w*ix;
        k10x += b.x*ix - b.y*iy;  k10y += b.x*iy + b.y*ix;
        k11x += b.z*ix;           k11y += b.z*iy;
    }
    const float nx = k01x*k10x - k01y*k10y;
    const float ny = k01x*k10y + k01y*k10x;
    const float dpx = 1.f + k11x, dpy = k11y;
    const float idq = frcp(dpx*dpx + dpy*dpy);
    const float qx = (nx*dpx + ny*dpy) * idq;
    const float qy = (ny*dpx - nx*dpy) * idq;
    const float rx = k00x - qx, ry = k00y - qy;
    ar_out[(size_t)d * LLEN + l] = make_float2(ccx*rx - ccy*ry, ccx*ry + ccy*rx);
}

// ---- K_mix: blocks [0,256) = Khat from a (2x FFT2048 via even/odd identity);
//      blocks [256, 256+8192) = transpose u tiles ------------------------------
__global__ __launch_bounds__(256, 4) void k_mix(const float* __restrict__ u,
                                                const float2* __restrict__ a_in,
                                                float* __restrict__ ut,
                                                float2* __restrict__ Hc) {
    __shared__ float2 X[LDSN2];
    const int tid = threadIdx.x;

    if (blockIdx.x >= DMODEL) {
        const int blk = blockIdx.x - DMODEL;
        const int bt0 = (blk & 1023) * 32;
        const int ch0 = (blk >> 10) * 32;
        float* tile = (float*)X;   // 32x33 floats
        const int tx = tid & 31, ty = tid >> 5;
#pragma unroll
        for (int k = 0; k < 4; ++k) {
            const int r = ty + 8 * k;
            tile[r * 33 + tx] = u[(size_t)(bt0 + r) * DMODEL + ch0 + tx];
        }
        __syncthreads();
#pragma unroll
        for (int k = 0; k < 4; ++k) {
            const int r = ty + 8 * k;
            ut[(size_t)(ch0 + r) * (NBATCH * LLEN) + bt0 + tx] = tile[tx * 33 + r];
        }
        return;
    }

    const int d = blockIdx.x;
    const float isc = 1.f / (float)NFFT;
    // load a (float4 = 2 complex at a time)
    const float4* a4 = (const float4*)(a_in + (size_t)d * LLEN);
#pragma unroll
    for (int k = 0; k < 4; ++k) {
        const int v = tid + k * 256;
        const float4 w = a4[v];
        X[PADIDX(2 * v)]     = make_float2(w.x, w.y);
        X[PADIDX(2 * v + 1)] = make_float2(w.z, w.w);
    }
    __syncthreads();

    float2* H = Hc + (size_t)d * KSTRIDE;
    // even frequencies: Khat_{2m} = (a_{(-m) mod L} + conj(a_m)) / 2
    for (int m = tid; m <= 1024; m += 256) {
        const float2 am = X[PADIDX(m)];
        const float2 an = X[PADIDX((LLEN - m) & (LLEN - 1))];
        H[2 * m] = make_float2((an.x + am.x) * 0.5f * isc,
                               (an.y - am.y) * 0.5f * isc);
    }
    // (no barrier needed: fft2048 stage0 reads first, barriers before writing)
    fft2048_f2<-1>(X, tid);     // A = F(a)

    // K_j = Re(A_j)/L ; modulate by e^{-2*pi*i*j/4096}
#pragma unroll
    for (int k = 0; k < 8; ++k) {
        const int j = tid + k * 256;
        const int q = PADIDX(j);
        const float Kj = X[q].x * (1.f / (float)LLEN);
        float snj, csj;
        __sincosf(-PI_F * (float)j * (1.f / 1024.f), &snj, &csj);
        X[q] = make_float2(Kj * csj, Kj * snj);
    }
    __syncthreads();
    fft2048_f2<-1>(X, tid);     // W_m = Khat_{2m+1}

    for (int m = tid; m < 1024; m += 256) {
        const float2 w = X[PADIDX(m)];
        H[2 * m + 1] = make_float2(w.x * isc, w.y * isc);
    }
}

// ---- K_conv: per (channel, batch-pair); H Hermitian: only f<=2048 stored -----
__global__ __launch_bounds__(256, 4) void k_conv(const float* __restrict__ ut,
                                                 const float2* __restrict__ Hc,
                                                 float* __restrict__ yt) {
    __shared__ float2 X[LDSN];
    const int ch = blockIdx.x >> 3, pair = blockIdx.x & 7, tid = threadIdx.x;
    const float4* u0 = (const float4*)(ut + (size_t)ch * (NBATCH * LLEN) + (size_t)(2 * pair) * LLEN);
    const float4* u1 = u0 + LLEN / 4;
#pragma unroll
    for (int k = 0; k < 2; ++k) {
        const int v4 = tid + k * 256;
        const float4 a = u0[v4], b = u1[v4];
        const int base = 4 * v4;
        X[PADIDX(base + 0)] = make_float2(a.x, b.x);
        X[PADIDX(base + 1)] = make_float2(a.y, b.y);
        X[PADIDX(base + 2)] = make_float2(a.z, b.z);
        X[PADIDX(base + 3)] = make_float2(a.w, b.w);
    }
    __syncthreads();
    fft4096_f2<-1, true, false>(X, tid);

    const float2* H = Hc + (size_t)ch * KSTRIDE;
    for (int f = tid; f <= NFFT / 2; f += 256) {
        const int fb = (NFFT - f) & (NFFT - 1);
        const float2 Za = X[PADIDX(f)], Zb = X[PADIDX(fb)];
        const float u0x = 0.5f * (Za.x + Zb.x), u0y = 0.5f * (Za.y - Zb.y);
        const float u1x = 0.5f * (Za.y + Zb.y), u1y = -0.5f * (Za.x - Zb.x);
        const float2 Ha = H[f];
        const float y0x = u0x*Ha.x - u0y*Ha.y, y0y = u0x*Ha.y + u0y*Ha.x;
        const float y1x = u1x*Ha.x - u1y*Ha.y, y1y = u1x*Ha.y + u1y*Ha.x;
        X[PADIDX(f)] = make_float2(y0x - y1y, y0y + y1x);
        if (fb != f) {
            const float Hbx = Ha.x, Hby = -Ha.y;   // H[fb] = conj(H[f]) (K real)
            const float z0x = u0x*Hbx + u0y*Hby, z0y = u0x*Hby - u0y*Hbx;
            const float z1x = u1x*Hbx + u1y*Hby, z1y = u1x*Hby - u1y*Hbx;
            X[PADIDX(fb)] = make_float2(z0x - z1y, z0y + z1x);
        }
    }
    __syncthreads();
    fft4096_f2<+1, false, true>(X, tid);   // pruned: only t<2048 stored

    float* y0o = yt + (size_t)ch * (NBATCH * LLEN) + (size_t)(2 * pair) * LLEN;
    float* y1o = y0o + LLEN;
    for (int i = tid; i < LLEN; i += 256) {
        const float2 v = X[PADIDX(i)];
        y0o[i] = v.x;
        y1o[i] = v.y;
    }
}

// ---- K_post: transpose back + skip -------------------------------------------
__global__ __launch_bounds__(256) void k_post(const float* __restrict__ yt,
                                              const float* __restrict__ u,
                                              const float* __restrict__ Dp,
                                              float* __restrict__ out) {
    __shared__ float tile[32][33];
    const int bt0 = blockIdx.x * 32, ch0 = blockIdx.y * 32;
    const int tx = threadIdx.x, ty = threadIdx.y;
    for (int k = 0; k < 4; ++k) {
        const int r = ty + 8 * k;
        tile[r][tx] = yt[(size_t)(ch0 + r) * (NBATCH * LLEN) + bt0 + tx];
    }
    __syncthreads();
    const float dp = Dp[ch0 + tx];
    for (int k = 0; k < 4; ++k) {
        const int r = ty + 8 * k;
        const size_t idx = (size_t)(bt0 + r) * DMODEL + ch0 + tx;
        out[idx] = tile[tx][r] + dp * u[idx];
    }
}

extern "C" void kernel_launch(void* const* d_in, const int* in_sizes, int n_in,
                              void* d_out, int out_size, void* d_ws, size_t ws_size,
                              hipStream_t stream) {
    const float* u         = (const float*)d_in[0];
    const float* p_ri      = (const float*)d_in[1];
    const float* lambda_ri = (const float*)d_in[2];
    const float* B_ri      = (const float*)d_in[3];
    const float* Ct_ri     = (const float*)d_in[4];
    const float* Dp        = (const float*)d_in[5];
    const float* log_step  = (const float*)d_in[6];
    float* out = (float*)d_out;

    // ws layout: Hc (256*2056 f2 = 4.21 MB) | region B: a (4 MB) aliased by yt (33.5 MB)
    // (a is dead once k_mix completes; k_conv then writes yt over it)
    float2* Hc = (float2*)d_ws;
    char*   wb = (char*)d_ws + (size_t)DMODEL * KSTRIDE * sizeof(float2);
    float2* a  = (float2*)wb;
    float*  yt = (float*)wb;
    float*  ut = out;   // d_out doubles as transpose scratch (fully overwritten by k_post)

    k_ar  <<<DMODEL * 8, 256, 0, stream>>>(p_ri, lambda_ri, B_ri, Ct_ri, log_step, a);
    k_mix <<<DMODEL + 8192, 256, 0, stream>>>(u, a, ut, Hc);
    k_conv<<<DMODEL * (NBATCH / 2), 256, 0, stream>>>(ut, Hc, yt);
    k_post<<<dim3(NBATCH * LLEN / 32, DMODEL / 32), dim3(32, 8), 0, stream>>>(yt, u, Dp, out);
}